// Round 1
// baseline (320.859 us; speedup 1.0000x reference)
//
#include <hip/hip_runtime.h>

// ZBL pair potential + segment-sum into NUM_SYSTEMS bins.
// Inputs (setup_inputs order):
//  0: local_d_ij               float32 [16M]
//  1: radii_table              float32 [97]
//  2: local_pair_indices       int32   [2, 16M]  (row 0 = idx_i, row 1 = idx_j)
//  3: atomic_numbers           int32   [1M]
//  4: atomic_subsystem_indices int32   [1M]
// Output: float32 [10000] per-system energy.
//
// R2:  LDS histograms + tree reduction (global atomics were the R1 serializer).
// R3-R8: MLP / branchless / compaction / agent-scope ALL NEUTRAL (120-131us);
//   nt (L2-bypass) = 333us. Model: ~16M distinct random line-requests served
//   at ~64 in-flight misses/CU x L2/L3 latency => latency floor, policy/scope/
//   MLP independent. Levers: request count, per-request latency.
// R9: physics-gated j-gather elision (d >= r_i + RMAX => phi = 0, skip j).
// R10 (this round): halve the gather working set. subsys is SORTED, so
//   seg(i) = seg_base[i>>6] + delta with delta < 512 (Poisson(0.64)
//   boundaries per 64-atom window). packed16[i] = z(7b) | delta(9b)<<7
//   is a 2 MB array serving BOTH i-gathers (z+segdelta) and j-gathers (z);
//   seg_base (31.25 KB u16) sits in LDS. 4 MB -> 2 MB hot set should turn
//   L3-hit gathers into L2 hits. Also fused reduce1+reduce2 (one launch less).

constexpr int MAXZ = 97;
constexpr int NBINS_PAD = 10240;   // 10000 bins padded for float4 flush
constexpr int NREP = 512;          // histogram replicas = grid of main kernel
constexpr int NPART = 32;          // (fallback-path constant, unused in main)
constexpr int WIN_SHIFT = 6;       // 64-atom seg-base windows
constexpr int NWIN_MAX = 15632;    // LDS seg-base capacity (1M atoms -> 15625)

constexpr double LOG2E_D = 1.4426950408889634;
constexpr float A_INV = (float)(1.0 / (0.8854 * 0.0529177210903));
constexpr float C1 = (float)(-3.2    * LOG2E_D);
constexpr float C2 = (float)(-0.9423 * LOG2E_D);
constexpr float C3 = (float)(-0.4029 * LOG2E_D);
constexpr float C4 = (float)(-0.2016 * LOG2E_D);
constexpr float COUL = 138.9354576f;
constexpr float RMAX = 0.26f;      // max radius in table (Z=87); r_j <= RMAX

typedef int   iv4 __attribute__((ext_vector_type(4)));
typedef float fv4 __attribute__((ext_vector_type(4)));
typedef float fv2 __attribute__((ext_vector_type(2)));

__global__ void zero_kernel(float* __restrict__ out, int n) {
    int i = blockIdx.x * blockDim.x + threadIdx.x;
    if (i < n) out[i] = 0.0f;
}

// ---- R10 pack: packed16[i] = z | (seg(i) - seg_base[i>>6]) << 7 ----------
__global__ void pack16_kernel(const int* __restrict__ z,
                              const int* __restrict__ seg,
                              unsigned short* __restrict__ p16,
                              unsigned short* __restrict__ segb, int n) {
    int i = blockIdx.x * blockDim.x + threadIdx.x;
    if (i < n) {
        int s = seg[i];
        int base = seg[(i >> WIN_SHIFT) << WIN_SHIFT];  // broadcast read
        p16[i] = (unsigned short)((unsigned)z[i] | ((unsigned)(s - base) << 7));
        if ((i & ((1 << WIN_SHIFT) - 1)) == 0)
            segb[i >> WIN_SHIFT] = (unsigned short)s;
    }
}

// packed[i] = z | (seg << 8)  (fallback path only)
__global__ void pack_kernel(const int* __restrict__ z,
                            const int* __restrict__ seg,
                            unsigned int* __restrict__ packed, int n) {
    int i = blockIdx.x * blockDim.x + threadIdx.x;
    if (i < n)
        packed[i] = (unsigned int)z[i] | ((unsigned int)seg[i] << 8);
}

// Edge-energy math given both z's (tables in LDS). pass=false => contributes 0.
__device__ __forceinline__ float zbl_energy(int zi, int zj, float d,
                                            const fv2* s_rz, bool& pass) {
    fv2 rzi = s_rz[zi];
    fv2 rzj = s_rz[zj];
    float rsum = rzi.x + rzj.x;
    pass = (d < rsum);
    float dA = d * (rzi.y + rzj.y) * A_INV;
    float f = 0.1818f  * __builtin_exp2f(C1 * dA)
            + 0.5099f  * __builtin_exp2f(C2 * dA)
            + 0.2802f  * __builtin_exp2f(C3 * dA)
            + 0.02817f * __builtin_exp2f(C4 * dA);
    float tt = d * __builtin_amdgcn_rcpf(rsum);          // in [0,1)
    // cos(pi*t) = v_cos(t/2)  (v_cos input is in revolutions)
    float phi = 0.5f * (__builtin_amdgcn_cosf(0.5f * tt) + 1.0f);
    return f * phi * (COUL * (float)zi * (float)zj) * __builtin_amdgcn_rcpf(d);
}

// ---------------- main path: LDS histogram, no global atomics ---------------

__global__ __launch_bounds__(1024)
void zbl_hist_kernel(const float* __restrict__ d_ij,
                     const float* __restrict__ radii,
                     const int* __restrict__ idx_i,
                     const int* __restrict__ idx_j,
                     const unsigned short* __restrict__ p16,
                     const unsigned short* __restrict__ segb_g,
                     int nwin,
                     float* __restrict__ rep,     // [NREP][NBINS_PAD]
                     int n_edges) {
    __shared__ float s_hist[NBINS_PAD];            // 40.96 KiB
    __shared__ fv2 s_rz[128];                      // {radius, z^0.23}
    __shared__ unsigned short s_segb[NWIN_MAX];    // 31.26 KiB seg window bases
    const int t = threadIdx.x;

    for (int b = t; b < NBINS_PAD; b += 1024) s_hist[b] = 0.0f;
    for (int b = t; b < nwin; b += 1024) s_segb[b] = segb_g[b];
    if (t < 128) {
        fv2 v;
        v.x = (t < MAXZ) ? radii[t] : 0.0f;
        v.y = __builtin_exp2f(0.23f * __builtin_log2f((float)t));  // z^0.23
        s_rz[t] = v;
    }
    __syncthreads();

    const int ngrp = n_edges >> 3;   // groups of 8 edges
    const int stride = gridDim.x * blockDim.x;
    for (int g = blockIdx.x * blockDim.x + t; g < ngrp; g += stride) {
        const iv4* pii = reinterpret_cast<const iv4*>(idx_i) + 2 * g;
        const iv4* pjj = reinterpret_cast<const iv4*>(idx_j) + 2 * g;
        const fv4* pdd = reinterpret_cast<const fv4*>(d_ij) + 2 * g;
        // Non-temporal stream loads: lines fully consumed once.
        iv4 ii0 = __builtin_nontemporal_load(pii);
        iv4 ii1 = __builtin_nontemporal_load(pii + 1);
        iv4 jj0 = __builtin_nontemporal_load(pjj);
        iv4 jj1 = __builtin_nontemporal_load(pjj + 1);
        fv4 dd0 = __builtin_nontemporal_load(pdd);
        fv4 dd1 = __builtin_nontemporal_load(pdd + 1);

        int ia[8], ja[8];
        float da[8];
#pragma unroll
        for (int k = 0; k < 4; ++k) {
            ia[k] = ii0[k]; ia[4 + k] = ii1[k];
            ja[k] = jj0[k]; ja[4 + k] = jj1[k];
            da[k] = dd0[k]; da[4 + k] = dd1[k];
        }

        // Phase 1: all 8 i-gathers back-to-back (2-byte, 2 MB hot array).
        // Dead lanes (i>=j) read p16[0] — one always-hot line, free.
        unsigned int pia[8];
        bool m[8];
#pragma unroll
        for (int k = 0; k < 8; ++k) {
            m[k] = ia[k] < ja[k];
            pia[k] = p16[m[k] ? ia[k] : 0];
        }

        // Phase 2: physics gate — r_j <= RMAX, so d >= r_i + RMAX implies
        // phi = 0 regardless of j. Elide those j-gathers (mask to p16[0]).
        bool need[8];
        unsigned int pja[8];
#pragma unroll
        for (int k = 0; k < 8; ++k) {
            int zi = (int)(pia[k] & 127u);
            float ri = s_rz[zi].x;
            need[k] = m[k] && (da[k] < ri + RMAX);
            pja[k] = p16[need[k] ? ja[k] : 0];
        }

        // Phase 3: compute + LDS accumulate for surviving edges.
#pragma unroll
        for (int k = 0; k < 8; ++k) {
            if (need[k]) {
                int zi = (int)(pia[k] & 127u);
                int zj = (int)(pja[k] & 127u);
                bool pass;
                float e = zbl_energy(zi, zj, da[k], s_rz, pass);
                if (pass) {
                    int seg = (int)s_segb[ia[k] >> WIN_SHIFT]
                            + (int)(pia[k] >> 7);
                    atomicAdd(&s_hist[seg], e);
                }
            }
        }
    }

    // Tail (n_edges % 8 != 0): at most 7 edges, one thread handles them.
    if (blockIdx.x == 0 && t == 0) {
        for (int e = ngrp << 3; e < n_edges; ++e) {
            int i = idx_i[e], j = idx_j[e];
            if (i < j) {
                unsigned int pi = p16[i], pj = p16[j];
                bool pass;
                float en = zbl_energy((int)(pi & 127u), (int)(pj & 127u),
                                      d_ij[e], s_rz, pass);
                if (pass) {
                    int seg = (int)segb_g[i >> WIN_SHIFT] + (int)(pi >> 7);
                    atomicAdd(&s_hist[seg], en);
                }
            }
        }
    }

    __syncthreads();
    // Flush histogram to this block's replica row (coalesced float4 stores).
    fv4* __restrict__ rp =
        reinterpret_cast<fv4*>(rep + (size_t)blockIdx.x * NBINS_PAD);
    const fv4* sh = reinterpret_cast<const fv4*>(s_hist);
    for (int q = t; q < NBINS_PAD / 4; q += 1024)
        rp[q] = sh[q];
}

// Fused reduce: out[bin] = sum over all NREP replica rows (one launch).
__global__ __launch_bounds__(256)
void reduce_all_kernel(const float* __restrict__ rep,
                       float* __restrict__ out, int out_size) {
    int bin = blockIdx.x * 256 + threadIdx.x;
    const float* p = rep + bin;
    float a0 = 0.f, a1 = 0.f, a2 = 0.f, a3 = 0.f;
    float a4 = 0.f, a5 = 0.f, a6 = 0.f, a7 = 0.f;
    for (int r = 0; r < NREP; r += 8) {
        a0 += p[(size_t)(r + 0) * NBINS_PAD];
        a1 += p[(size_t)(r + 1) * NBINS_PAD];
        a2 += p[(size_t)(r + 2) * NBINS_PAD];
        a3 += p[(size_t)(r + 3) * NBINS_PAD];
        a4 += p[(size_t)(r + 4) * NBINS_PAD];
        a5 += p[(size_t)(r + 5) * NBINS_PAD];
        a6 += p[(size_t)(r + 6) * NBINS_PAD];
        a7 += p[(size_t)(r + 7) * NBINS_PAD];
    }
    float s = ((a0 + a1) + (a2 + a3)) + ((a4 + a5) + (a6 + a7));
    if (bin < out_size) out[bin] = s;
}

// ---------------- fallback path (R1): direct global atomics ----------------

template <bool PACKED>
__global__ __launch_bounds__(256)
void zbl_atomic_kernel(const float* __restrict__ d_ij,
                       const float* __restrict__ radii,
                       const int* __restrict__ idx_i,
                       const int* __restrict__ idx_j,
                       const unsigned int* __restrict__ packed,
                       const int* __restrict__ atomz,
                       const int* __restrict__ subsys,
                       float* __restrict__ out,
                       int nchunk) {
    __shared__ fv2 s_rz[128];
    int t = threadIdx.x;
    if (t < 128) {
        fv2 v;
        v.x = (t < MAXZ) ? radii[t] : 0.0f;
        v.y = __builtin_exp2f(0.23f * __builtin_log2f((float)t));
        s_rz[t] = v;
    }
    __syncthreads();

    int chunk = blockIdx.x * blockDim.x + threadIdx.x;
    if (chunk >= nchunk) return;

    iv4 ii = reinterpret_cast<const iv4*>(idx_i)[chunk];
    iv4 jj = reinterpret_cast<const iv4*>(idx_j)[chunk];
    fv4 dd = reinterpret_cast<const fv4*>(d_ij)[chunk];

#pragma unroll
    for (int k = 0; k < 4; ++k) {
        int i = ii[k];
        int j = jj[k];
        float d = dd[k];
        if (i < j) {
            int zi, zj, seg;
            if (PACKED) {
                unsigned int pi = packed[i];
                unsigned int pj = packed[j];
                zi = (int)(pi & 0xFFu);
                zj = (int)(pj & 0xFFu);
                seg = (int)(pi >> 8);
            } else {
                zi = atomz[i];
                zj = atomz[j];
                seg = subsys[i];
            }
            bool pass;
            float e = zbl_energy(zi, zj, d, s_rz, pass);
            if (pass) atomicAdd(out + seg, e);
        }
    }
}

extern "C" void kernel_launch(void* const* d_in, const int* in_sizes, int n_in,
                              void* d_out, int out_size, void* d_ws, size_t ws_size,
                              hipStream_t stream) {
    const float* d_ij  = (const float*)d_in[0];
    const float* radii = (const float*)d_in[1];
    const int* pairs   = (const int*)d_in[2];
    const int* atomz   = (const int*)d_in[3];
    const int* subsys  = (const int*)d_in[4];
    float* out = (float*)d_out;

    const int n_edges = in_sizes[2] / 2;   // 16,000,000
    const int n_atoms = in_sizes[3];       // 1,000,000
    const int* idx_i = pairs;
    const int* idx_j = pairs + n_edges;

    const int nwin = (n_atoms + (1 << WIN_SHIFT) - 1) >> WIN_SHIFT;
    const size_t p16_bytes  = ((size_t)n_atoms * 2 + 255) & ~(size_t)255;
    const size_t segb_bytes = ((size_t)nwin * 2 + 255) & ~(size_t)255;
    const size_t rep_bytes  = (size_t)NREP * NBINS_PAD * sizeof(float);
    const size_t packed_bytes = (size_t)n_atoms * sizeof(unsigned int);

    if (nwin <= NWIN_MAX &&
        ws_size >= p16_bytes + segb_bytes + rep_bytes) {
        unsigned short* p16  = (unsigned short*)d_ws;
        unsigned short* segb = (unsigned short*)((char*)d_ws + p16_bytes);
        float* rep = (float*)((char*)d_ws + p16_bytes + segb_bytes);

        pack16_kernel<<<(n_atoms + 255) / 256, 256, 0, stream>>>(
            atomz, subsys, p16, segb, n_atoms);
        zbl_hist_kernel<<<NREP, 1024, 0, stream>>>(
            d_ij, radii, idx_i, idx_j, p16, segb, nwin, rep, n_edges);
        reduce_all_kernel<<<NBINS_PAD / 256, 256, 0, stream>>>(
            rep, out, out_size);
    } else {
        // Fallback: direct-atomic path (R1)
        zero_kernel<<<(out_size + 255) / 256, 256, 0, stream>>>(out, out_size);
        const int nchunk = n_edges / 4;
        const int blocks = (nchunk + 255) / 256;
        if (ws_size >= packed_bytes) {
            unsigned int* packed = (unsigned int*)d_ws;
            pack_kernel<<<(n_atoms + 255) / 256, 256, 0, stream>>>(
                atomz, subsys, packed, n_atoms);
            zbl_atomic_kernel<true><<<blocks, 256, 0, stream>>>(
                d_ij, radii, idx_i, idx_j, packed, atomz, subsys, out, nchunk);
        } else {
            zbl_atomic_kernel<false><<<blocks, 256, 0, stream>>>(
                d_ij, radii, idx_i, idx_j, nullptr, atomz, subsys, out, nchunk);
        }
    }
}

// Round 3
// 300.656 us; speedup vs baseline: 1.0672x; 1.0672x over previous
//
#include <hip/hip_runtime.h>

// ZBL pair potential + segment-sum into NUM_SYSTEMS bins.
// Inputs (setup_inputs order):
//  0: local_d_ij               float32 [16M]
//  1: radii_table              float32 [97]
//  2: local_pair_indices       int32   [2, 16M]  (row 0 = idx_i, row 1 = idx_j)
//  3: atomic_numbers           int32   [1M]
//  4: atomic_subsystem_indices int32   [1M]
// Output: float32 [10000] per-system energy.
//
// R2:  LDS histograms + tree reduction (global atomics were the R1 serializer).
// R3-R8: MLP / branchless / compaction / agent-scope ALL NEUTRAL (120-131us);
//   nt (L2-bypass) = 333us. Model: ~14.5M distinct random line-requests at
//   ~64 in-flight misses/CU x ~220-270cyc latency => latency floor; policy/
//   scope/MLP independent. Levers: request count, per-request latency.
// R9:  physics-gated j-gather elision (d >= r_i + RMAX => phi = 0, skip j).
// R10: p16 working set 4MB->2MB (seg delta vs LDS window bases). hist
//   118 -> 108.5us, FETCH 152->106MB (gathers now L2/L3-resident). CONFIRMED.
// R11: REVERT the fused reduce_all (R10's one regression): 10240 threads x
//   512 strided loads was latency-serial (~+20us vs the two-stage tree).
//   Restore reduce1 (NPART=32 fan-in, 1280 blocks, BW-bound) + reduce2.
// R12 (this round): identical resubmission — R11 bench failed on container
//   acquisition (infra), no kernel signal.

constexpr int MAXZ = 97;
constexpr int NBINS_PAD = 10240;   // 10000 bins padded for float4 flush
constexpr int NREP = 512;          // histogram replicas = grid of main kernel
constexpr int NPART = 32;          // first-stage reduction fan-in groups
constexpr int WIN_SHIFT = 6;       // 64-atom seg-base windows
constexpr int NWIN_MAX = 15632;    // LDS seg-base capacity (1M atoms -> 15625)

constexpr double LOG2E_D = 1.4426950408889634;
constexpr float A_INV = (float)(1.0 / (0.8854 * 0.0529177210903));
constexpr float C1 = (float)(-3.2    * LOG2E_D);
constexpr float C2 = (float)(-0.9423 * LOG2E_D);
constexpr float C3 = (float)(-0.4029 * LOG2E_D);
constexpr float C4 = (float)(-0.2016 * LOG2E_D);
constexpr float COUL = 138.9354576f;
constexpr float RMAX = 0.26f;      // max radius in table (Z=87); r_j <= RMAX

typedef int   iv4 __attribute__((ext_vector_type(4)));
typedef float fv4 __attribute__((ext_vector_type(4)));
typedef float fv2 __attribute__((ext_vector_type(2)));

__global__ void zero_kernel(float* __restrict__ out, int n) {
    int i = blockIdx.x * blockDim.x + threadIdx.x;
    if (i < n) out[i] = 0.0f;
}

// ---- pack: p16[i] = z | (seg(i) - seg_base[i>>6]) << 7 --------------------
__global__ void pack16_kernel(const int* __restrict__ z,
                              const int* __restrict__ seg,
                              unsigned short* __restrict__ p16,
                              unsigned short* __restrict__ segb, int n) {
    int i = blockIdx.x * blockDim.x + threadIdx.x;
    if (i < n) {
        int s = seg[i];
        int base = seg[(i >> WIN_SHIFT) << WIN_SHIFT];  // broadcast read
        p16[i] = (unsigned short)((unsigned)z[i] | ((unsigned)(s - base) << 7));
        if ((i & ((1 << WIN_SHIFT) - 1)) == 0)
            segb[i >> WIN_SHIFT] = (unsigned short)s;
    }
}

// packed[i] = z | (seg << 8)  (fallback path only)
__global__ void pack_kernel(const int* __restrict__ z,
                            const int* __restrict__ seg,
                            unsigned int* __restrict__ packed, int n) {
    int i = blockIdx.x * blockDim.x + threadIdx.x;
    if (i < n)
        packed[i] = (unsigned int)z[i] | ((unsigned int)seg[i] << 8);
}

// Edge-energy math given both z's (tables in LDS). pass=false => contributes 0.
__device__ __forceinline__ float zbl_energy(int zi, int zj, float d,
                                            const fv2* s_rz, bool& pass) {
    fv2 rzi = s_rz[zi];
    fv2 rzj = s_rz[zj];
    float rsum = rzi.x + rzj.x;
    pass = (d < rsum);
    float dA = d * (rzi.y + rzj.y) * A_INV;
    float f = 0.1818f  * __builtin_exp2f(C1 * dA)
            + 0.5099f  * __builtin_exp2f(C2 * dA)
            + 0.2802f  * __builtin_exp2f(C3 * dA)
            + 0.02817f * __builtin_exp2f(C4 * dA);
    float tt = d * __builtin_amdgcn_rcpf(rsum);          // in [0,1)
    // cos(pi*t) = v_cos(t/2)  (v_cos input is in revolutions)
    float phi = 0.5f * (__builtin_amdgcn_cosf(0.5f * tt) + 1.0f);
    return f * phi * (COUL * (float)zi * (float)zj) * __builtin_amdgcn_rcpf(d);
}

// ---------------- main path: LDS histogram, no global atomics ---------------

__global__ __launch_bounds__(1024)
void zbl_hist_kernel(const float* __restrict__ d_ij,
                     const float* __restrict__ radii,
                     const int* __restrict__ idx_i,
                     const int* __restrict__ idx_j,
                     const unsigned short* __restrict__ p16,
                     const unsigned short* __restrict__ segb_g,
                     int nwin,
                     float* __restrict__ rep,     // [NREP][NBINS_PAD]
                     int n_edges) {
    __shared__ float s_hist[NBINS_PAD];            // 40.96 KiB
    __shared__ fv2 s_rz[128];                      // {radius, z^0.23}
    __shared__ unsigned short s_segb[NWIN_MAX];    // 31.26 KiB seg window bases
    const int t = threadIdx.x;

    for (int b = t; b < NBINS_PAD; b += 1024) s_hist[b] = 0.0f;
    for (int b = t; b < nwin; b += 1024) s_segb[b] = segb_g[b];
    if (t < 128) {
        fv2 v;
        v.x = (t < MAXZ) ? radii[t] : 0.0f;
        v.y = __builtin_exp2f(0.23f * __builtin_log2f((float)t));  // z^0.23
        s_rz[t] = v;
    }
    __syncthreads();

    const int ngrp = n_edges >> 3;   // groups of 8 edges
    const int stride = gridDim.x * blockDim.x;
    for (int g = blockIdx.x * blockDim.x + t; g < ngrp; g += stride) {
        const iv4* pii = reinterpret_cast<const iv4*>(idx_i) + 2 * g;
        const iv4* pjj = reinterpret_cast<const iv4*>(idx_j) + 2 * g;
        const fv4* pdd = reinterpret_cast<const fv4*>(d_ij) + 2 * g;
        // Non-temporal stream loads: lines fully consumed once.
        iv4 ii0 = __builtin_nontemporal_load(pii);
        iv4 ii1 = __builtin_nontemporal_load(pii + 1);
        iv4 jj0 = __builtin_nontemporal_load(pjj);
        iv4 jj1 = __builtin_nontemporal_load(pjj + 1);
        fv4 dd0 = __builtin_nontemporal_load(pdd);
        fv4 dd1 = __builtin_nontemporal_load(pdd + 1);

        int ia[8], ja[8];
        float da[8];
#pragma unroll
        for (int k = 0; k < 4; ++k) {
            ia[k] = ii0[k]; ia[4 + k] = ii1[k];
            ja[k] = jj0[k]; ja[4 + k] = jj1[k];
            da[k] = dd0[k]; da[4 + k] = dd1[k];
        }

        // Phase 1: all 8 i-gathers back-to-back (2-byte, 2 MB hot array).
        // Dead lanes (i>=j) read p16[0] — one always-hot line, free.
        unsigned int pia[8];
        bool m[8];
#pragma unroll
        for (int k = 0; k < 8; ++k) {
            m[k] = ia[k] < ja[k];
            pia[k] = p16[m[k] ? ia[k] : 0];
        }

        // Phase 2: physics gate — r_j <= RMAX, so d >= r_i + RMAX implies
        // phi = 0 regardless of j. Elide those j-gathers (mask to p16[0]).
        bool need[8];
        unsigned int pja[8];
#pragma unroll
        for (int k = 0; k < 8; ++k) {
            int zi = (int)(pia[k] & 127u);
            float ri = s_rz[zi].x;
            need[k] = m[k] && (da[k] < ri + RMAX);
            pja[k] = p16[need[k] ? ja[k] : 0];
        }

        // Phase 3: compute + LDS accumulate for surviving edges.
#pragma unroll
        for (int k = 0; k < 8; ++k) {
            if (need[k]) {
                int zi = (int)(pia[k] & 127u);
                int zj = (int)(pja[k] & 127u);
                bool pass;
                float e = zbl_energy(zi, zj, da[k], s_rz, pass);
                if (pass) {
                    int seg = (int)s_segb[ia[k] >> WIN_SHIFT]
                            + (int)(pia[k] >> 7);
                    atomicAdd(&s_hist[seg], e);
                }
            }
        }
    }

    // Tail (n_edges % 8 != 0): at most 7 edges, one thread handles them.
    if (blockIdx.x == 0 && t == 0) {
        for (int e = ngrp << 3; e < n_edges; ++e) {
            int i = idx_i[e], j = idx_j[e];
            if (i < j) {
                unsigned int pi = p16[i], pj = p16[j];
                bool pass;
                float en = zbl_energy((int)(pi & 127u), (int)(pj & 127u),
                                      d_ij[e], s_rz, pass);
                if (pass) {
                    int seg = (int)segb_g[i >> WIN_SHIFT] + (int)(pi >> 7);
                    atomicAdd(&s_hist[seg], en);
                }
            }
        }
    }

    __syncthreads();
    // Flush histogram to this block's replica row (coalesced float4 stores).
    fv4* __restrict__ rp =
        reinterpret_cast<fv4*>(rep + (size_t)blockIdx.x * NBINS_PAD);
    const fv4* sh = reinterpret_cast<const fv4*>(s_hist);
    for (int q = t; q < NBINS_PAD / 4; q += 1024)
        rp[q] = sh[q];
}

// Stage 1: partial[s][bin] = sum over replica rows r = s, s+NPART, ...
// 1280 blocks -> ample TLP, BW-bound on the 21 MB rep read.
__global__ __launch_bounds__(256)
void reduce1_kernel(const float* __restrict__ rep,
                    float* __restrict__ partial) {
    int bin = blockIdx.x * 256 + threadIdx.x;
    int s = blockIdx.y;
    float acc = 0.0f;
    for (int r = s; r < NREP; r += NPART)
        acc += rep[(size_t)r * NBINS_PAD + bin];
    partial[(size_t)s * NBINS_PAD + bin] = acc;
}

// Stage 2: out[bin] = sum over NPART partials.
__global__ __launch_bounds__(256)
void reduce2_kernel(const float* __restrict__ partial,
                    float* __restrict__ out, int out_size) {
    int bin = blockIdx.x * 256 + threadIdx.x;
    if (bin < out_size) {
        float acc = 0.0f;
        for (int s = 0; s < NPART; ++s)
            acc += partial[(size_t)s * NBINS_PAD + bin];
        out[bin] = acc;
    }
}

// ---------------- fallback path (R1): direct global atomics ----------------

template <bool PACKED>
__global__ __launch_bounds__(256)
void zbl_atomic_kernel(const float* __restrict__ d_ij,
                       const float* __restrict__ radii,
                       const int* __restrict__ idx_i,
                       const int* __restrict__ idx_j,
                       const unsigned int* __restrict__ packed,
                       const int* __restrict__ atomz,
                       const int* __restrict__ subsys,
                       float* __restrict__ out,
                       int nchunk) {
    __shared__ fv2 s_rz[128];
    int t = threadIdx.x;
    if (t < 128) {
        fv2 v;
        v.x = (t < MAXZ) ? radii[t] : 0.0f;
        v.y = __builtin_exp2f(0.23f * __builtin_log2f((float)t));
        s_rz[t] = v;
    }
    __syncthreads();

    int chunk = blockIdx.x * blockDim.x + threadIdx.x;
    if (chunk >= nchunk) return;

    iv4 ii = reinterpret_cast<const iv4*>(idx_i)[chunk];
    iv4 jj = reinterpret_cast<const iv4*>(idx_j)[chunk];
    fv4 dd = reinterpret_cast<const fv4*>(d_ij)[chunk];

#pragma unroll
    for (int k = 0; k < 4; ++k) {
        int i = ii[k];
        int j = jj[k];
        float d = dd[k];
        if (i < j) {
            int zi, zj, seg;
            if (PACKED) {
                unsigned int pi = packed[i];
                unsigned int pj = packed[j];
                zi = (int)(pi & 0xFFu);
                zj = (int)(pj & 0xFFu);
                seg = (int)(pi >> 8);
            } else {
                zi = atomz[i];
                zj = atomz[j];
                seg = subsys[i];
            }
            bool pass;
            float e = zbl_energy(zi, zj, d, s_rz, pass);
            if (pass) atomicAdd(out + seg, e);
        }
    }
}

extern "C" void kernel_launch(void* const* d_in, const int* in_sizes, int n_in,
                              void* d_out, int out_size, void* d_ws, size_t ws_size,
                              hipStream_t stream) {
    const float* d_ij  = (const float*)d_in[0];
    const float* radii = (const float*)d_in[1];
    const int* pairs   = (const int*)d_in[2];
    const int* atomz   = (const int*)d_in[3];
    const int* subsys  = (const int*)d_in[4];
    float* out = (float*)d_out;

    const int n_edges = in_sizes[2] / 2;   // 16,000,000
    const int n_atoms = in_sizes[3];       // 1,000,000
    const int* idx_i = pairs;
    const int* idx_j = pairs + n_edges;

    const int nwin = (n_atoms + (1 << WIN_SHIFT) - 1) >> WIN_SHIFT;
    const size_t p16_bytes  = ((size_t)n_atoms * 2 + 255) & ~(size_t)255;
    const size_t segb_bytes = ((size_t)nwin * 2 + 255) & ~(size_t)255;
    const size_t rep_bytes  = (size_t)NREP * NBINS_PAD * sizeof(float);
    const size_t part_bytes = (size_t)NPART * NBINS_PAD * sizeof(float);
    const size_t packed_bytes = (size_t)n_atoms * sizeof(unsigned int);

    if (nwin <= NWIN_MAX &&
        ws_size >= p16_bytes + segb_bytes + rep_bytes + part_bytes) {
        unsigned short* p16  = (unsigned short*)d_ws;
        unsigned short* segb = (unsigned short*)((char*)d_ws + p16_bytes);
        float* rep = (float*)((char*)d_ws + p16_bytes + segb_bytes);
        float* partial = (float*)((char*)d_ws + p16_bytes + segb_bytes +
                                  rep_bytes);

        pack16_kernel<<<(n_atoms + 255) / 256, 256, 0, stream>>>(
            atomz, subsys, p16, segb, n_atoms);
        zbl_hist_kernel<<<NREP, 1024, 0, stream>>>(
            d_ij, radii, idx_i, idx_j, p16, segb, nwin, rep, n_edges);
        dim3 g1(NBINS_PAD / 256, NPART);
        reduce1_kernel<<<g1, 256, 0, stream>>>(rep, partial);
        reduce2_kernel<<<(out_size + 255) / 256, 256, 0, stream>>>(
            partial, out, out_size);
    } else {
        // Fallback: direct-atomic path (R1)
        zero_kernel<<<(out_size + 255) / 256, 256, 0, stream>>>(out, out_size);
        const int nchunk = n_edges / 4;
        const int blocks = (nchunk + 255) / 256;
        if (ws_size >= packed_bytes) {
            unsigned int* packed = (unsigned int*)d_ws;
            pack_kernel<<<(n_atoms + 255) / 256, 256, 0, stream>>>(
                atomz, subsys, packed, n_atoms);
            zbl_atomic_kernel<true><<<blocks, 256, 0, stream>>>(
                d_ij, radii, idx_i, idx_j, packed, atomz, subsys, out, nchunk);
        } else {
            zbl_atomic_kernel<false><<<blocks, 256, 0, stream>>>(
                d_ij, radii, idx_i, idx_j, nullptr, atomz, subsys, out, nchunk);
        }
    }
}